// Round 7
// baseline (16832.928 us; speedup 1.0000x reference)
//
#include <hip/hip_runtime.h>
#include <math.h>

#define T_SEQ 4096
#define I_DIM 1024
#define H_DIM 2048
#define O_DIM 512
#define G4    8192   // 4*H

// ---------------------------------------------------------------------------
// Phase 1: xg[t, perm(r)] = sum_k input[t,k]*W_ih[r,k] + b_ih[r] + b_hh[r]
// perm(r): r = g*2048 + 8*q + j  ->  t*8192 + q*32 + g*8 + j
// so that LSTM block b (=q) reads its 32 gate values contiguously.
// Tiled fp32 GEMM: 128x128 tile, BK=16, 256 threads, 8x8 microtile.
// ---------------------------------------------------------------------------
__global__ __launch_bounds__(256) void gemm_xg(
    const float* __restrict__ A, const float* __restrict__ W,
    const float* __restrict__ b_ih, const float* __restrict__ b_hh,
    float* __restrict__ xg)
{
  __shared__ __align__(16) float As[16][132];
  __shared__ __align__(16) float Bs[16][132];
  const int tid = threadIdx.x;
  const int t0 = blockIdx.y * 128;
  const int r0 = blockIdx.x * 128;
  const int tx = tid & 15, ty = tid >> 4;

  float acc[8][8];
  #pragma unroll
  for (int i = 0; i < 8; ++i)
    #pragma unroll
    for (int j = 0; j < 8; ++j) acc[i][j] = 0.f;

  for (int k0 = 0; k0 < I_DIM; k0 += 16) {
    #pragma unroll
    for (int i = 0; i < 2; ++i) {
      int lin = tid + i * 256;     // 0..511
      int row = lin >> 2;          // 0..127
      int kq  = (lin & 3) << 2;    // 0,4,8,12
      float4 va = *(const float4*)&A[(size_t)(t0 + row) * I_DIM + k0 + kq];
      As[kq+0][row] = va.x; As[kq+1][row] = va.y; As[kq+2][row] = va.z; As[kq+3][row] = va.w;
      float4 vb = *(const float4*)&W[(size_t)(r0 + row) * I_DIM + k0 + kq];
      Bs[kq+0][row] = vb.x; Bs[kq+1][row] = vb.y; Bs[kq+2][row] = vb.z; Bs[kq+3][row] = vb.w;
    }
    __syncthreads();
    #pragma unroll
    for (int kk = 0; kk < 16; ++kk) {
      float4 a0 = *(const float4*)&As[kk][ty*8];
      float4 a1 = *(const float4*)&As[kk][ty*8+4];
      float4 b0 = *(const float4*)&Bs[kk][tx*8];
      float4 b1 = *(const float4*)&Bs[kk][tx*8+4];
      float av[8] = {a0.x,a0.y,a0.z,a0.w,a1.x,a1.y,a1.z,a1.w};
      float bv[8] = {b0.x,b0.y,b0.z,b0.w,b1.x,b1.y,b1.z,b1.w};
      #pragma unroll
      for (int i = 0; i < 8; ++i)
        #pragma unroll
        for (int j = 0; j < 8; ++j)
          acc[i][j] = fmaf(av[i], bv[j], acc[i][j]);
    }
    __syncthreads();
  }

  const int rbase = r0 + tx * 8;          // multiple of 8
  const int g = rbase >> 11;              // gate 0..3 (constant over 8 cols)
  const int q = (rbase & 2047) >> 3;      // 8-row group = LSTM block id
  float bias[8];
  #pragma unroll
  for (int j = 0; j < 8; ++j) bias[j] = b_ih[rbase + j] + b_hh[rbase + j];
  #pragma unroll
  for (int i = 0; i < 8; ++i) {
    int t = t0 + ty * 8 + i;
    float* dst = &xg[(size_t)t * G4 + q * 32 + g * 8];
    float4 o0 = make_float4(acc[i][0]+bias[0], acc[i][1]+bias[1], acc[i][2]+bias[2], acc[i][3]+bias[3]);
    float4 o1 = make_float4(acc[i][4]+bias[4], acc[i][5]+bias[5], acc[i][6]+bias[6], acc[i][7]+bias[7]);
    *(float4*)&dst[0] = o0;
    *(float4*)&dst[4] = o1;
  }
}

// fast activations (lane 0 only, but on the serial critical path)
__device__ __forceinline__ float sigf(float x) {
  return 1.f / (1.f + __expf(-x));
}
__device__ __forceinline__ float tanh_fast(float x) {
  return 1.f - 2.f / (__expf(2.f * x) + 1.f);   // saturates correctly
}

// ---------------------------------------------------------------------------
// Phase 2: persistent LSTM recurrence, self-announcing (value,tag) pairs,
// two-level exchange through the per-XCD L2:
//   producers : lane0 of each wave stores its 8B pair sc0 sc1 (LLC-visible)
//   gateways  : ONE block per XCD (elected via atomicAdd; XCD from
//               HW_REG_XCC_ID) polls the LLC for all 2048 tags, then
//               re-stores the pairs into its XCD mailbox with PLAIN stores
//               (C++ uint4 stores -> global_store_dwordx4, no sc bits).
//               CDNA L1 is write-through -> the data lands in the XCD's
//               shared L2 immediately.
//   siblings  : poll the mailbox with sc0-only loads (L1 bypass, L2 hit)
//               at ~3-5x lower latency than the LLC path; fall back to
//               direct LLC polling if the mailbox stalls (mapping guard).
// Tags ride with values in aligned 8B pairs (stores tear at worst at 8B
// boundaries -> each pair stays atomic). No flags, no fences, no L2
// maintenance anywhere in the loop.
// Overwrite safety (2 parities): a producer overwrites LLC slot of h_t at
// step t+2 only after seeing ALL h_{t+1} tags; h_{t+1} completeness
// transitively requires every gateway (the only LLC readers) to have
// finished reading h_t, and every sibling to have finished its mailbox
// read of h_t. Same argument covers mailbox parities and the two LDS
// broadcast buffers around the single per-step barrier.
// ---------------------------------------------------------------------------
__global__ __launch_bounds__(512, 2) void lstm_seq(
    const float* __restrict__ W_hh, const float* __restrict__ xg,
    uint2* __restrict__ hbuf /* 2*2048 pairs (LLC) */,
    uint2* __restrict__ mail /* 8 XCDs * 2*2048 pairs (L2 mailboxes) */,
    int*   __restrict__ gwcnt /* 8 election counters */)
{
  __shared__ __align__(16) float smem[21000];  // 84000 B -> forces 1 block/CU
  float* hsh = smem;                           // 2 x 2048 broadcast buffers
  __shared__ int s_gw;                         // 1 = this block is a gateway
  __shared__ int s_xcc;

  const int tid  = threadIdx.x;
  const int b    = blockIdx.x;     // 0..255
  const int lane = tid & 63;
  const int w    = tid >> 6;       // wave id = h element index within block

  if (tid == 0) {
    unsigned xcc;
    asm volatile("s_getreg_b32 %0, hwreg(HW_REG_XCC_ID, 0, 32)" : "=s"(xcc));
    xcc &= 7;
    s_xcc = (int)xcc;
    s_gw  = (atomicAdd(&gwcnt[xcc], 1) == 0) ? 1 : 0;
  }
  __syncthreads();
  const int  xcc   = s_xcc;
  const bool is_gw = (s_gw != 0);
  uint2* mb_base = mail + (xcc << 12);   // my XCD's mailbox: 2 parities x 2048

  // Weights: 4 gate rows of h-element 8b+w; cols 4*lane + 256*k, k=0..7.
  float4 wt[4][8];
  #pragma unroll
  for (int g = 0; g < 4; ++g) {
    const float* wr = &W_hh[(size_t)(g * H_DIM + 8 * b + w) * H_DIM + 4 * lane];
    #pragma unroll
    for (int k = 0; k < 8; ++k) wt[g][k] = *(const float4*)&wr[256 * k];
  }

  float c_reg = 0.f;          // cell state (lane 0 of each wave)
  bool gaveup = false;        // hang safety valve
  bool use_llc = false;       // sibling fallback: poll LLC directly

  // preload xg for t = 0 (uniform addresses; only lane 0 consumes)
  const float* xp0 = &xg[(size_t)0 * G4 + b * 32 + w];
  float xgi = xp0[0], xgf = xp0[8], xgg = xp0[16], xgo = xp0[24];

  for (int t = 0; t < T_SEQ; ++t) {
    const int par = t & 1;
    const unsigned tag = (unsigned)t;
    const uint2* ha = hbuf + (par << 11) + 256 * w + 4 * lane;      // LLC slice
    uint2*       ma = mb_base + (par << 11) + 256 * w + 4 * lane;   // L2 slice

    uint4 f0, f1;
    if (is_gw) {
      // gateway: poll LLC until my 4 tags == t
      int tries = 0;
      for (;;) {
        asm volatile("global_load_dwordx4 %0, %2, off sc0 sc1\n\t"
                     "global_load_dwordx4 %1, %3, off sc0 sc1\n\t"
                     "s_waitcnt vmcnt(0)"
                     : "=&v"(f0), "=&v"(f1)
                     : "v"(ha), "v"(ha + 2)
                     : "memory");
        bool ok = (f0.y == tag) & (f0.w == tag) & (f1.y == tag) & (f1.w == tag);
        if (__all(ok) || gaveup) break;
        if (++tries > (1 << 20)) { gaveup = true; break; }
      }
      // re-publish my slice into the XCD mailbox: PLAIN stores (no sc bits),
      // write-through L1 -> shared L2. Ordering after the poll is kept by
      // the poll asm's "memory" clobber.
      ((uint4*)ma)[0] = f0;
      ((uint4*)ma)[1] = f1;
    } else {
      // sibling: poll the XCD mailbox at L2 latency (sc0 = L1 bypass only)
      int tries = 0;
      for (;;) {
        if (!use_llc) {
          asm volatile("global_load_dwordx4 %0, %2, off sc0\n\t"
                       "global_load_dwordx4 %1, %3, off sc0\n\t"
                       "s_waitcnt vmcnt(0)"
                       : "=&v"(f0), "=&v"(f1)
                       : "v"(ma), "v"(ma + 2)
                       : "memory");
          bool ok = (f0.y == tag) & (f0.w == tag) & (f1.y == tag) & (f1.w == tag);
          if (__all(ok) || gaveup) break;
          if (++tries > (1 << 14)) { use_llc = true; tries = 0; }  // guard
        } else {
          asm volatile("global_load_dwordx4 %0, %2, off sc0 sc1\n\t"
                       "global_load_dwordx4 %1, %3, off sc0 sc1\n\t"
                       "s_waitcnt vmcnt(0)"
                       : "=&v"(f0), "=&v"(f1)
                       : "v"(ha), "v"(ha + 2)
                       : "memory");
          bool ok = (f0.y == tag) & (f0.w == tag) & (f1.y == tag) & (f1.w == tag);
          if (__all(ok) || gaveup) break;
          if (++tries > (1 << 20)) { gaveup = true; break; }
        }
      }
    }

    // broadcast values into this step's LDS buffer
    float* hd = hsh + (par << 11);
    float4 hv4 = make_float4(__uint_as_float(f0.x), __uint_as_float(f0.z),
                             __uint_as_float(f1.x), __uint_as_float(f1.z));
    *(float4*)&hd[256 * w + 4 * lane] = hv4;

    // prefetch xg for step t+1 (independent; consumed at loop tail so the
    // compiler's waitcnt for it lands off the poll path)
    float nxi = 0.f, nxf = 0.f, nxg = 0.f, nxo = 0.f;
    if (t + 1 < T_SEQ) {
      const float* xp = &xg[(size_t)(t + 1) * G4 + b * 32 + w];
      nxi = xp[0]; nxf = xp[8]; nxg = xp[16]; nxo = xp[24];
    }

    __syncthreads();   // the ONE barrier per step

    // dot products: 4 gate rows x 32 cols per lane
    float s0 = 0.f, s1 = 0.f, s2 = 0.f, s3 = 0.f;
    #pragma unroll
    for (int k = 0; k < 8; ++k) {
      float4 hv = *(const float4*)&hd[4 * lane + 256 * k];
      s0 = fmaf(wt[0][k].x, hv.x, s0); s0 = fmaf(wt[0][k].y, hv.y, s0);
      s0 = fmaf(wt[0][k].z, hv.z, s0); s0 = fmaf(wt[0][k].w, hv.w, s0);
      s1 = fmaf(wt[1][k].x, hv.x, s1); s1 = fmaf(wt[1][k].y, hv.y, s1);
      s1 = fmaf(wt[1][k].z, hv.z, s1); s1 = fmaf(wt[1][k].w, hv.w, s1);
      s2 = fmaf(wt[2][k].x, hv.x, s2); s2 = fmaf(wt[2][k].y, hv.y, s2);
      s2 = fmaf(wt[2][k].z, hv.z, s2); s2 = fmaf(wt[2][k].w, hv.w, s2);
      s3 = fmaf(wt[3][k].x, hv.x, s3); s3 = fmaf(wt[3][k].y, hv.y, s3);
      s3 = fmaf(wt[3][k].z, hv.z, s3); s3 = fmaf(wt[3][k].w, hv.w, s3);
    }

    // butterfly reduce 4 values across 64 lanes
    #pragma unroll
    for (int sh = 32; sh >= 1; sh >>= 1) {
      s0 += __shfl_xor(s0, sh, 64);
      s1 += __shfl_xor(s1, sh, 64);
      s2 += __shfl_xor(s2, sh, 64);
      s3 += __shfl_xor(s3, sh, 64);
    }

    // lane 0: gate math + ONE packed (value, tag) store to the LLC
    if (lane == 0) {
      float iv = sigf(s0 + xgi);
      float fv = sigf(s1 + xgf);
      float gv = tanh_fast(s2 + xgg);
      float ov = sigf(s3 + xgo);
      c_reg = fv * c_reg + iv * gv;
      float hv = ov * tanh_fast(c_reg);
      uint2 pv;
      pv.x = __float_as_uint(hv);
      pv.y = (unsigned)(t + 1);
      uint2* dst = hbuf + (((t + 1) & 1) << 11) + 8 * b + w;
      asm volatile("global_store_dwordx2 %0, %1, off sc0 sc1"
                   :: "v"(dst), "v"(pv) : "memory");
    }

    xgi = nxi; xgf = nxf; xgg = nxg; xgo = nxo;
  }
}

// ---------------------------------------------------------------------------
// Phase 3: out[o] = h_last . W_lin[o,:] + b_lin[o]. One wave per output.
// h_last = values of the LLC pairs at parity 0 (step 4095 writes parity 0).
// ---------------------------------------------------------------------------
__global__ __launch_bounds__(256) void proj_out(
    const float* __restrict__ W_lin, const float* __restrict__ b_lin,
    const uint2* __restrict__ hpairs, float* __restrict__ out)
{
  const int tid = threadIdx.x;
  const int lane = tid & 63;
  const int w4 = tid >> 6;
  const int o = blockIdx.x * 4 + w4;
  const float* wr = &W_lin[(size_t)o * H_DIM + 4 * lane];
  float s = 0.f;
  #pragma unroll
  for (int k = 0; k < 8; ++k) {
    float4 wv = *(const float4*)&wr[256 * k];
    uint4 p0 = *(const uint4*)&hpairs[4 * lane + 256 * k];       // v,t,v,t
    uint4 p1 = *(const uint4*)&hpairs[4 * lane + 256 * k + 2];   // v,t,v,t
    s = fmaf(wv.x, __uint_as_float(p0.x), s);
    s = fmaf(wv.y, __uint_as_float(p0.z), s);
    s = fmaf(wv.z, __uint_as_float(p1.x), s);
    s = fmaf(wv.w, __uint_as_float(p1.z), s);
  }
  #pragma unroll
  for (int sh = 32; sh >= 1; sh >>= 1) s += __shfl_xor(s, sh, 64);
  if (lane == 0) out[o] = s + b_lin[o];
}

// ---------------------------------------------------------------------------
extern "C" void kernel_launch(void* const* d_in, const int* in_sizes, int n_in,
                              void* d_out, int out_size, void* d_ws, size_t ws_size,
                              hipStream_t stream)
{
  const float* input = (const float*)d_in[0];
  const float* W_ih  = (const float*)d_in[1];
  const float* W_hh  = (const float*)d_in[2];
  const float* b_ih  = (const float*)d_in[3];
  const float* b_hh  = (const float*)d_in[4];
  const float* W_lin = (const float*)d_in[5];
  const float* b_lin = (const float*)d_in[6];
  float* out = (float*)d_out;

  char* ws = (char*)d_ws;
  const size_t XG_BYTES   = (size_t)T_SEQ * G4 * sizeof(float);     // 128 MB
  const size_t HB_BYTES   = 2ull * H_DIM * sizeof(uint2);           // 32 KB
  const size_t MAIL_BYTES = 8ull * 2 * H_DIM * sizeof(uint2);       // 256 KB
  float* xg    = (float*)ws;
  uint2* hbuf  = (uint2*)(ws + XG_BYTES);
  uint2* mail  = (uint2*)(ws + XG_BYTES + HB_BYTES);
  int*   gwcnt = (int*)  (ws + XG_BYTES + HB_BYTES + MAIL_BYTES);

  // zero pairs (h_0 = 0 with tag 0), mailboxes, and election counters
  (void)hipMemsetAsync(ws + XG_BYTES, 0, HB_BYTES + MAIL_BYTES + 8 * sizeof(int), stream);

  gemm_xg<<<dim3(64, 32), 256, 0, stream>>>(input, W_ih, b_ih, b_hh, xg);
  lstm_seq<<<256, 512, 0, stream>>>(W_hh, xg, hbuf, mail, gwcnt);
  proj_out<<<128, 256, 0, stream>>>(W_lin, b_lin, hbuf, out);
}

// Round 8
// 11540.132 us; speedup vs baseline: 1.4586x; 1.4586x over previous
//
#include <hip/hip_runtime.h>
#include <math.h>

#define T_SEQ 4096
#define I_DIM 1024
#define H_DIM 2048
#define O_DIM 512
#define G4    8192   // 4*H

// ---------------------------------------------------------------------------
// Phase 1: xg[t, perm(r)] = sum_k input[t,k]*W_ih[r,k] + b_ih[r] + b_hh[r]
// perm(r): r = g*2048 + 8*q + j  ->  t*8192 + q*32 + g*8 + j
// so that LSTM block b (=q) reads its 32 gate values contiguously.
// Tiled fp32 GEMM: 128x128 tile, BK=16, 256 threads, 8x8 microtile.
// ---------------------------------------------------------------------------
__global__ __launch_bounds__(256) void gemm_xg(
    const float* __restrict__ A, const float* __restrict__ W,
    const float* __restrict__ b_ih, const float* __restrict__ b_hh,
    float* __restrict__ xg)
{
  __shared__ __align__(16) float As[16][132];
  __shared__ __align__(16) float Bs[16][132];
  const int tid = threadIdx.x;
  const int t0 = blockIdx.y * 128;
  const int r0 = blockIdx.x * 128;
  const int tx = tid & 15, ty = tid >> 4;

  float acc[8][8];
  #pragma unroll
  for (int i = 0; i < 8; ++i)
    #pragma unroll
    for (int j = 0; j < 8; ++j) acc[i][j] = 0.f;

  for (int k0 = 0; k0 < I_DIM; k0 += 16) {
    #pragma unroll
    for (int i = 0; i < 2; ++i) {
      int lin = tid + i * 256;     // 0..511
      int row = lin >> 2;          // 0..127
      int kq  = (lin & 3) << 2;    // 0,4,8,12
      float4 va = *(const float4*)&A[(size_t)(t0 + row) * I_DIM + k0 + kq];
      As[kq+0][row] = va.x; As[kq+1][row] = va.y; As[kq+2][row] = va.z; As[kq+3][row] = va.w;
      float4 vb = *(const float4*)&W[(size_t)(r0 + row) * I_DIM + k0 + kq];
      Bs[kq+0][row] = vb.x; Bs[kq+1][row] = vb.y; Bs[kq+2][row] = vb.z; Bs[kq+3][row] = vb.w;
    }
    __syncthreads();
    #pragma unroll
    for (int kk = 0; kk < 16; ++kk) {
      float4 a0 = *(const float4*)&As[kk][ty*8];
      float4 a1 = *(const float4*)&As[kk][ty*8+4];
      float4 b0 = *(const float4*)&Bs[kk][tx*8];
      float4 b1 = *(const float4*)&Bs[kk][tx*8+4];
      float av[8] = {a0.x,a0.y,a0.z,a0.w,a1.x,a1.y,a1.z,a1.w};
      float bv[8] = {b0.x,b0.y,b0.z,b0.w,b1.x,b1.y,b1.z,b1.w};
      #pragma unroll
      for (int i = 0; i < 8; ++i)
        #pragma unroll
        for (int j = 0; j < 8; ++j)
          acc[i][j] = fmaf(av[i], bv[j], acc[i][j]);
    }
    __syncthreads();
  }

  const int rbase = r0 + tx * 8;          // multiple of 8
  const int g = rbase >> 11;              // gate 0..3 (constant over 8 cols)
  const int q = (rbase & 2047) >> 3;      // 8-row group = LSTM block id
  float bias[8];
  #pragma unroll
  for (int j = 0; j < 8; ++j) bias[j] = b_ih[rbase + j] + b_hh[rbase + j];
  #pragma unroll
  for (int i = 0; i < 8; ++i) {
    int t = t0 + ty * 8 + i;
    float* dst = &xg[(size_t)t * G4 + q * 32 + g * 8];
    float4 o0 = make_float4(acc[i][0]+bias[0], acc[i][1]+bias[1], acc[i][2]+bias[2], acc[i][3]+bias[3]);
    float4 o1 = make_float4(acc[i][4]+bias[4], acc[i][5]+bias[5], acc[i][6]+bias[6], acc[i][7]+bias[7]);
    *(float4*)&dst[0] = o0;
    *(float4*)&dst[4] = o1;
  }
}

// fast activations (lane 0 only, but on the serial critical path)
__device__ __forceinline__ float sigf(float x) {
  return 1.f / (1.f + __expf(-x));
}
__device__ __forceinline__ float tanh_fast(float x) {
  return 1.f - 2.f / (__expf(2.f * x) + 1.f);   // saturates correctly
}

// ---------------------------------------------------------------------------
// Phase 2: persistent LSTM recurrence, self-announcing (value,tag) pairs,
// NREP-way replicated (round-5 structure) -- PLUS register-pinned weights.
// KEY FIX (round 8): VGPR_Count was 88 in every prior round, i.e. the
// compiler SANK the loop-invariant weight loads into the t-loop: 64 MB of
// W_hh re-fetched from L2/LLC every step = ~24 TB/s sustained -- the kernel
// was cache-BW-bound on weight re-fetch, not sync-bound. We force the
// 128-float slice into VGPRs by pinning each scalar with an opaque
// asm "+v" (32-bit scalars: legal constraint; makes remat-from-memory
// impossible). Budget: 128 + ~80 < 256 VGPRs (__launch_bounds__(512,2)).
// Everything else is identical to round 5 (best verified: 10.8 ms).
// ---------------------------------------------------------------------------
__global__ __launch_bounds__(512, 2) void lstm_seq(
    const float* __restrict__ W_hh, const float* __restrict__ xg,
    uint2* __restrict__ hbuf, int nrep)
{
  __shared__ __align__(16) float smem[21000];  // 84000 B -> forces 1 block/CU
  float* hsh = smem;                           // 2 x 2048 broadcast buffers

  const int tid  = threadIdx.x;
  const int b    = blockIdx.x;     // 0..255
  const int lane = tid & 63;
  const int w    = tid >> 6;       // wave id = h element index within block
  const int pstr = nrep << 11;     // pairs per parity
  const int myrep = b & (nrep - 1);

  // Weights: 4 gate rows of h-element 8b+w; cols 4*lane + 256*k, k=0..7.
  // Loaded once, scattered to 128 scalars, PINNED in VGPRs via opaque asm.
  float wr[128];
  #pragma unroll
  for (int g = 0; g < 4; ++g) {
    const float* wp = &W_hh[(size_t)(g * H_DIM + 8 * b + w) * H_DIM + 4 * lane];
    #pragma unroll
    for (int k = 0; k < 8; ++k) {
      float4 v = *(const float4*)&wp[256 * k];
      wr[g * 32 + k * 4 + 0] = v.x;
      wr[g * 32 + k * 4 + 1] = v.y;
      wr[g * 32 + k * 4 + 2] = v.z;
      wr[g * 32 + k * 4 + 3] = v.w;
    }
  }
  #pragma unroll
  for (int i = 0; i < 128; ++i)
    asm volatile("" : "+v"(wr[i]));   // opaque def: must stay in a register

  float c_reg = 0.f;          // cell state (lane 0 of each wave)
  bool gaveup = false;        // hang safety valve

  // preload xg for t = 0 (uniform addresses; only lane 0 consumes)
  const float* xp0 = &xg[(size_t)0 * G4 + b * 32 + w];
  float xgi = xp0[0], xgf = xp0[8], xgg = xp0[16], xgo = xp0[24];

  for (int t = 0; t < T_SEQ; ++t) {
    const uint2* hb = hbuf + (t & 1) * pstr + (myrep << 11);  // my replica of h_t
    const unsigned tag = (unsigned)t;

    // 1) poll my 4 pairs (16B + 16B) until all 4 tags == t
    const uint2* a0 = hb + 256 * w + 4 * lane;
    uint4 f0, f1;
    int tries = 0;
    for (;;) {
      asm volatile("global_load_dwordx4 %0, %2, off sc0 sc1\n\t"
                   "global_load_dwordx4 %1, %3, off sc0 sc1\n\t"
                   "s_waitcnt vmcnt(0)"
                   : "=&v"(f0), "=&v"(f1)
                   : "v"(a0), "v"(a0 + 2)
                   : "memory");
      bool ok = (f0.y == tag) & (f0.w == tag) & (f1.y == tag) & (f1.w == tag);
      if (__all(ok) || gaveup) break;
      if (++tries > (1 << 17)) { gaveup = true; break; }
    }

    // 2) broadcast values into this step's LDS buffer
    float* hd = hsh + ((t & 1) << 11);
    float4 hv4 = make_float4(__uint_as_float(f0.x), __uint_as_float(f0.z),
                             __uint_as_float(f1.x), __uint_as_float(f1.z));
    *(float4*)&hd[256 * w + 4 * lane] = hv4;

    // prefetch xg for step t+1 (independent; consumed at loop tail so the
    // compiler's waitcnt for it lands off the poll path)
    float nxi = 0.f, nxf = 0.f, nxg = 0.f, nxo = 0.f;
    if (t + 1 < T_SEQ) {
      const float* xp = &xg[(size_t)(t + 1) * G4 + b * 32 + w];
      nxi = xp[0]; nxf = xp[8]; nxg = xp[16]; nxo = xp[24];
    }

    __syncthreads();   // the ONE barrier per step

    // 3) dot products: 4 gate rows x 32 cols per lane (weights in VGPRs)
    float s0 = 0.f, s1 = 0.f, s2 = 0.f, s3 = 0.f;
    #pragma unroll
    for (int k = 0; k < 8; ++k) {
      float4 hv = *(const float4*)&hd[4 * lane + 256 * k];
      s0 = fmaf(wr[0*32+k*4+0], hv.x, s0); s0 = fmaf(wr[0*32+k*4+1], hv.y, s0);
      s0 = fmaf(wr[0*32+k*4+2], hv.z, s0); s0 = fmaf(wr[0*32+k*4+3], hv.w, s0);
      s1 = fmaf(wr[1*32+k*4+0], hv.x, s1); s1 = fmaf(wr[1*32+k*4+1], hv.y, s1);
      s1 = fmaf(wr[1*32+k*4+2], hv.z, s1); s1 = fmaf(wr[1*32+k*4+3], hv.w, s1);
      s2 = fmaf(wr[2*32+k*4+0], hv.x, s2); s2 = fmaf(wr[2*32+k*4+1], hv.y, s2);
      s2 = fmaf(wr[2*32+k*4+2], hv.z, s2); s2 = fmaf(wr[2*32+k*4+3], hv.w, s2);
      s3 = fmaf(wr[3*32+k*4+0], hv.x, s3); s3 = fmaf(wr[3*32+k*4+1], hv.y, s3);
      s3 = fmaf(wr[3*32+k*4+2], hv.z, s3); s3 = fmaf(wr[3*32+k*4+3], hv.w, s3);
    }

    // butterfly reduce 4 values across 64 lanes
    #pragma unroll
    for (int sh = 32; sh >= 1; sh >>= 1) {
      s0 += __shfl_xor(s0, sh, 64);
      s1 += __shfl_xor(s1, sh, 64);
      s2 += __shfl_xor(s2, sh, 64);
      s3 += __shfl_xor(s3, sh, 64);
    }

    // 4) lane 0: gate math + nrep packed (value, tag) stores (one/replica)
    if (lane == 0) {
      float iv = sigf(s0 + xgi);
      float fv = sigf(s1 + xgf);
      float gv = tanh_fast(s2 + xgg);
      float ov = sigf(s3 + xgo);
      c_reg = fv * c_reg + iv * gv;
      float hv = ov * tanh_fast(c_reg);
      uint2 pv;
      pv.x = __float_as_uint(hv);
      pv.y = (unsigned)(t + 1);
      uint2* dst = hbuf + ((t + 1) & 1) * pstr + 8 * b + w;
      for (int r = 0; r < nrep; ++r) {
        asm volatile("global_store_dwordx2 %0, %1, off sc0 sc1"
                     :: "v"(dst), "v"(pv) : "memory");
        dst += 2048;
      }
    }

    xgi = nxi; xgf = nxf; xgg = nxg; xgo = nxo;
  }
}

// ---------------------------------------------------------------------------
// Phase 3: out[o] = h_last . W_lin[o,:] + b_lin[o]. One wave per output.
// h_last = values of replica-0 pairs at parity 0 (step 4095 writes par 0).
// ---------------------------------------------------------------------------
__global__ __launch_bounds__(256) void proj_out(
    const float* __restrict__ W_lin, const float* __restrict__ b_lin,
    const uint2* __restrict__ hpairs, float* __restrict__ out)
{
  const int tid = threadIdx.x;
  const int lane = tid & 63;
  const int w4 = tid >> 6;
  const int o = blockIdx.x * 4 + w4;
  const float* wr = &W_lin[(size_t)o * H_DIM + 4 * lane];
  float s = 0.f;
  #pragma unroll
  for (int k = 0; k < 8; ++k) {
    float4 wv = *(const float4*)&wr[256 * k];
    uint4 p0 = *(const uint4*)&hpairs[4 * lane + 256 * k];       // v,t,v,t
    uint4 p1 = *(const uint4*)&hpairs[4 * lane + 256 * k + 2];   // v,t,v,t
    s = fmaf(wv.x, __uint_as_float(p0.x), s);
    s = fmaf(wv.y, __uint_as_float(p0.z), s);
    s = fmaf(wv.z, __uint_as_float(p1.x), s);
    s = fmaf(wv.w, __uint_as_float(p1.z), s);
  }
  #pragma unroll
  for (int sh = 32; sh >= 1; sh >>= 1) s += __shfl_xor(s, sh, 64);
  if (lane == 0) out[o] = s + b_lin[o];
}

// ---------------------------------------------------------------------------
extern "C" void kernel_launch(void* const* d_in, const int* in_sizes, int n_in,
                              void* d_out, int out_size, void* d_ws, size_t ws_size,
                              hipStream_t stream)
{
  const float* input = (const float*)d_in[0];
  const float* W_ih  = (const float*)d_in[1];
  const float* W_hh  = (const float*)d_in[2];
  const float* b_ih  = (const float*)d_in[3];
  const float* b_hh  = (const float*)d_in[4];
  const float* W_lin = (const float*)d_in[5];
  const float* b_lin = (const float*)d_in[6];
  float* out = (float*)d_out;

  char* ws = (char*)d_ws;
  const size_t XG_BYTES = (size_t)T_SEQ * G4 * sizeof(float);   // 128 MB
  float* xg   = (float*)ws;
  uint2* hbuf = (uint2*)(ws + XG_BYTES);

  // 8 replicas if the workspace allows (2 parities x 8 replicas x 2048 pairs
  // x 8B = 256KB), else fall back to the single-copy layout.
  const size_t HB8 = 2ull * 8 * H_DIM * sizeof(uint2);
  int nrep = (ws_size >= XG_BYTES + HB8) ? 8 : 1;
  const size_t HB_BYTES = 2ull * nrep * H_DIM * sizeof(uint2);

  // zero all pair buffers: h_0 = 0 with tag 0 (= step-0 poll target)
  (void)hipMemsetAsync(ws + XG_BYTES, 0, HB_BYTES, stream);

  gemm_xg<<<dim3(64, 32), 256, 0, stream>>>(input, W_ih, b_ih, b_hh, xg);
  lstm_seq<<<256, 512, 0, stream>>>(W_hh, xg, hbuf, nrep);
  proj_out<<<128, 256, 0, stream>>>(W_lin, b_lin, hbuf, out);
}